// Round 15
// baseline (70.563 us; speedup 1.0000x reference)
//
#include <hip/hip_runtime.h>

// Analytic collapse (verified R1-R13, absmax <= 2e-3):
//   <Z_0> = c1*...*c7,  <Z_j> = c0*...*cj,  c_j = cos(t_j + theta_j)
// R14 = R13 + pre-split W (helper kernel -> d_ws) + direct-from-global x
// A-fragments (no x staging, no B1 barrier). Two kernels in the graph:
//  prep_w: splits Wq,Wk,Wv,Wo into packed bf16 hi/lo in d_ws (overwrites the
//          harness's 0xAA poison every call — same work each launch).
//  qattn:  512 blocks x 256 thr; 16 tokens/block; ~18 KB LDS; 2 barriers.
//   P1: A-frags = 4 global b128 of x + 8 bfsplit2 (once per wave);
//       B-frags = 4 global b128 of PRE-SPLIT W per job (zero split VALU);
//       3 jobs/wave, 6 MFMA each; cos + DPP-scan epilogue -> sP.
//   P2: R13's verified row-per-lane attention (4 tokens/wave, dup gated).
//   P3: scr A-frags from LDS (split-bf16), Wo B-frags pre-split; 6 MFMA.

typedef float  f32x4  __attribute__((ext_vector_type(4)));
typedef short  bf16x8 __attribute__((ext_vector_type(8)));
typedef unsigned short u16;
typedef unsigned int   u32;

#define WRS 72   // shorts per scr row (64 data + 8 pad) = 144 B
#define SPS 68   // sP row stride (dwords), 16B-aligned

// d *= dpp_row_shr<sh>(d) gated to lanes with (lane&7) >= sh
#define DPP_SHR_STEP(d, j, sh)                                                 \
    {                                                                          \
        float _t = __int_as_float(__builtin_amdgcn_update_dpp(                 \
            0x3f800000, __float_as_int(d), 0x110 + sh, 0xf, 0xf, false));      \
        d *= ((j) >= (sh)) ? _t : 1.0f;                                        \
    }

__device__ __forceinline__ u32 bfh(float f) {          // RTNE bf16 (raw u16)
    const u32 u = __float_as_uint(f);
    return (u + 0x7FFFu + ((u >> 16) & 1u)) >> 16;
}
// trunc-hi split of a pair, packed (R13-verified accuracy class ~2^-17)
__device__ __forceinline__ void bfsplit2(float a, float b, u32& h, u32& l) {
    const u32 ua = __float_as_uint(a), ub = __float_as_uint(b);
    h = (ua >> 16) | (ub & 0xFFFF0000u);
    const float ra = a - __uint_as_float(ua & 0xFFFF0000u);   // exact
    const float rb = b - __uint_as_float(ub & 0xFFFF0000u);   // exact
    l = bfh(ra) | (bfh(rb) << 16);
}
__device__ __forceinline__ bf16x8 mk8(u32 a, u32 b, u32 c, u32 d) {
    uint4 t = make_uint4(a, b, c, d);
    return *(bf16x8*)&t;
}
__device__ __forceinline__ void splitpack(const float4 w0, const float4 w1,
                                          bf16x8& hi, bf16x8& lo) {
    u32 h0, l0, h1, l1, h2, l2, h3, l3;
    bfsplit2(w0.x, w0.y, h0, l0);
    bfsplit2(w0.z, w0.w, h1, l1);
    bfsplit2(w1.x, w1.y, h2, l2);
    bfsplit2(w1.z, w1.w, h3, l3);
    hi = mk8(h0, h1, h2, h3);
    lo = mk8(l0, l1, l2, l3);
}

#define MFMA3(acc, ah, al, bh, bl)                                             \
    acc = __builtin_amdgcn_mfma_f32_16x16x32_bf16(al, bh, acc, 0, 0, 0);       \
    acc = __builtin_amdgcn_mfma_f32_16x16x32_bf16(ah, bl, acc, 0, 0, 0);       \
    acc = __builtin_amdgcn_mfma_f32_16x16x32_bf16(ah, bh, acc, 0, 0, 0);

// ---- helper: pre-split all 4 W matrices into packed bf16 hi/lo in d_ws ----
__global__ __launch_bounds__(256)
void prep_w(const float* __restrict__ wq, const float* __restrict__ wk,
            const float* __restrict__ wv, const float* __restrict__ wo,
            u16* __restrict__ whi, u16* __restrict__ wlo)
{
    const int g = blockIdx.x * 256 + threadIdx.x;      // float4 idx 0..4095
    const float* gm[4] = {wq, wk, wv, wo};
    const float4 v = ((const float4*)gm[g >> 10])[g & 1023];
    u32 h01, l01, h23, l23;
    bfsplit2(v.x, v.y, h01, l01);
    bfsplit2(v.z, v.w, h23, l23);
    *(uint2*)&whi[4 * g] = make_uint2(h01, h23);       // contiguous: 4g
    *(uint2*)&wlo[4 * g] = make_uint2(l01, l23);
}

__global__ __launch_bounds__(256, 4)
void qattn_fused(const float* __restrict__ xg,
                 const u16* __restrict__ whi, const u16* __restrict__ wlo,
                 const float* __restrict__ thg,
                 float* __restrict__ outg)
{
    __shared__ __align__(16) float sP[48 * SPS];   // 13 KB  z values [m*16+t][e]
    __shared__ u16 sSh[16 * WRS];                  // 2.3 KB scr hi [rho][col]
    __shared__ u16 sSl[16 * WRS];                  // 2.3 KB scr lo

    const int tid  = threadIdx.x;
    const int lane = tid & 63;
    const int wg   = tid >> 6;         // 0..3
    const int l15  = lane & 15;
    const int quad = lane >> 4;
    const int j    = lane & 7;
    const int b    = blockIdx.x >> 5;
    const int grp  = blockIdx.x & 31;  // 16-token group in batch row

    const float thf = thg[j];

    // ---- P1: A-frags direct from global x (fragment layout = row gather) ----
    {
        const float* xr = xg + (size_t)(b * 512 + grp * 16 + l15) * 64 + quad * 8;
        bf16x8 ah0, al0, ah1, al1;
        {
            const float4 x0 = *(const float4*)xr;
            const float4 x1 = *(const float4*)(xr + 4);
            splitpack(x0, x1, ah0, al0);               // k = quad*8 ..
        }
        {
            const float4 x0 = *(const float4*)(xr + 32);
            const float4 x1 = *(const float4*)(xr + 36);
            splitpack(x0, x1, ah1, al1);               // k = 32 + quad*8 ..
        }
        #pragma unroll
        for (int ia = 0; ia < 3; ++ia) {
            const int aid = wg * 3 + ia;               // 0..11
            const int m = aid >> 2, nt = aid & 3;
            const int off = ((m * 64 + nt * 16 + l15) * 64) + quad * 8;
            const bf16x8 bh0 = *(const bf16x8*)(whi + off);
            const bf16x8 bh1 = *(const bf16x8*)(whi + off + 32);
            const bf16x8 bl0 = *(const bf16x8*)(wlo + off);
            const bf16x8 bl1 = *(const bf16x8*)(wlo + off + 32);
            f32x4 acc = {0.f, 0.f, 0.f, 0.f};
            MFMA3(acc, ah0, al0, bh0, bl0)
            MFMA3(acc, ah1, al1, bh1, bl1)
            // epilogue: lane holds q[token][e], e = nt*16+l15; token=quad*4+r
            #pragma unroll
            for (int r = 0; r < 4; ++r) {
                const float c = __cosf(acc[r] + thf);
                float d = c;                           // inclusive scan (c0..cj)
                DPP_SHR_STEP(d, j, 1)
                DPP_SHR_STEP(d, j, 2)
                DPP_SHR_STEP(d, j, 4)
                float ex = (j == 0) ? 1.0f : c;        // scan excluding c0
                DPP_SHR_STEP(ex, j, 1)
                DPP_SHR_STEP(ex, j, 2)
                DPP_SHR_STEP(ex, j, 4)
                const int row  = m * 16 + quad * 4 + r;
                const int base = row * SPS + nt * 16 + l15;
                if (j > 0)  sP[base]     = d;          // z_j = c0..cj
                if (j == 7) sP[base - 7] = ex;         // z_0 = c1..c7 -> slot 0
            }
        }
    }
    __syncthreads();                                   // B1: z ready

    // ---- P2: row-per-lane attention; 4 tokens/wave, dup lanes gated ----
    {
        const int tg = wg * 4 + (lane >> 4);           // block-local token 0..15
        const int i  = j;                              // head (score row)
        const int qb = tg * SPS;
        const int kb = (16 + tg) * SPS;
        const int vb = (32 + tg) * SPS;
        float q[8];
        *(float4*)&q[0] = *(const float4*)&sP[qb + 8 * i];
        *(float4*)&q[4] = *(const float4*)&sP[qb + 8 * i + 4];
        float pr[8];
        float sum = 0.f;
        #pragma unroll
        for (int jj = 0; jj < 8; ++jj) {               // |s| <= 2.83 -> no max-sub
            const float4 k0 = *(const float4*)&sP[kb + 8 * jj];
            const float4 k1 = *(const float4*)&sP[kb + 8 * jj + 4];
            float s = q[0] * k0.x;
            s = fmaf(q[1], k0.y, s); s = fmaf(q[2], k0.z, s);
            s = fmaf(q[3], k0.w, s); s = fmaf(q[4], k1.x, s);
            s = fmaf(q[5], k1.y, s); s = fmaf(q[6], k1.z, s);
            s = fmaf(q[7], k1.w, s);
            pr[jj] = __expf(s * 0.35355339059327373f);
            sum += pr[jj];
        }
        const float rinv = 1.0f / sum;
        float o[8];
        #pragma unroll
        for (int w = 0; w < 8; ++w) o[w] = 0.f;
        #pragma unroll
        for (int jj = 0; jj < 8; ++jj) {
            const float4 v0 = *(const float4*)&sP[vb + 8 * jj];
            const float4 v1 = *(const float4*)&sP[vb + 8 * jj + 4];
            const float a = pr[jj] * rinv;
            o[0] = fmaf(a, v0.x, o[0]); o[1] = fmaf(a, v0.y, o[1]);
            o[2] = fmaf(a, v0.z, o[2]); o[3] = fmaf(a, v0.w, o[3]);
            o[4] = fmaf(a, v1.x, o[4]); o[5] = fmaf(a, v1.y, o[5]);
            o[6] = fmaf(a, v1.z, o[6]); o[7] = fmaf(a, v1.w, o[7]);
        }
        // scrambled row rho = i*2 + (tg>>3); col base 8*(tg&7); split-bf16
        if (!(lane & 8)) {
            u32 hh[4], ll[4];
            #pragma unroll
            for (int c = 0; c < 4; ++c)
                bfsplit2(o[2 * c], o[2 * c + 1], hh[c], ll[c]);
            const int so = (i * 2 + (tg >> 3)) * WRS + 8 * (tg & 7);
            *(uint4*)&sSh[so] = make_uint4(hh[0], hh[1], hh[2], hh[3]);
            *(uint4*)&sSl[so] = make_uint4(ll[0], ll[1], ll[2], ll[3]);
        }
    }
    __syncthreads();                                   // B2: scr ready

    // ---- P3: y = scr @ Wo^T via MFMA; 1 job/wave (nt2 = wg) ----
    {
        const int arow = l15 * WRS + quad * 8;
        const bf16x8 ah0 = *(const bf16x8*)&sSh[arow];
        const bf16x8 ah1 = *(const bf16x8*)&sSh[arow + 32];
        const bf16x8 al0 = *(const bf16x8*)&sSl[arow];
        const bf16x8 al1 = *(const bf16x8*)&sSl[arow + 32];
        const int off = ((3 * 64 + wg * 16 + l15) * 64) + quad * 8;
        const bf16x8 bh0 = *(const bf16x8*)(whi + off);
        const bf16x8 bh1 = *(const bf16x8*)(whi + off + 32);
        const bf16x8 bl0 = *(const bf16x8*)(wlo + off);
        const bf16x8 bl1 = *(const bf16x8*)(wlo + off + 32);
        f32x4 acc = {0.f, 0.f, 0.f, 0.f};
        MFMA3(acc, ah0, al0, bh0, bl0)
        MFMA3(acc, ah1, al1, bh1, bl1)
        // store: lane holds y[rho][e], rho = quad*4+r, e = wg*16+l15
        const int e = wg * 16 + l15;
        #pragma unroll
        for (int r = 0; r < 4; ++r) {
            const int rho = quad * 4 + r;
            const int R   = (rho >> 1) * 64 + grp * 2 + (rho & 1);
            outg[((size_t)(b * 512 + R)) * 64 + e] = acc[r];
        }
    }
}

extern "C" void kernel_launch(void* const* d_in, const int* in_sizes, int n_in,
                              void* d_out, int out_size, void* d_ws, size_t ws_size,
                              hipStream_t stream) {
    const float* x  = (const float*)d_in[0];
    const float* wq = (const float*)d_in[1];
    const float* wk = (const float*)d_in[2];
    const float* wv = (const float*)d_in[3];
    const float* wo = (const float*)d_in[4];
    const float* th = (const float*)d_in[5];
    float* out = (float*)d_out;
    u16* whi = (u16*)d_ws;              // 4*64*64 shorts = 32 KB
    u16* wlo = whi + 4 * 64 * 64;       // next 32 KB
    // pre-split W (overwrites d_ws poison every call; same work per launch)
    prep_w<<<dim3(16), dim3(256), 0, stream>>>(wq, wk, wv, wo, whi, wlo);
    // B=16, S=512: 16 batches x 32 sixteen-token groups = 512 blocks
    qattn_fused<<<dim3(512), dim3(256), 0, stream>>>(x, whi, wlo, th, out);
}

// Round 16
// 68.864 us; speedup vs baseline: 1.0247x; 1.0247x over previous
//
#include <hip/hip_runtime.h>

// Analytic collapse (verified R1-R14, absmax <= 2e-3):
//   <Z_0> = c1*...*c7,  <Z_j> = c0*...*cj,  c_j = cos(t_j + theta_j)
// R15 = R12 (best: 66.9 us) with two local reductions:
//  - staging in float8 chunks -> single b128 LDS write per buffer (halves
//    staging DS instruction count; DS pipe is the modeled bottleneck ~3 us)
//  - trunc-hi split (R13-verified, 1.95e-3) instead of double-RTNE
// Single kernel (R14 proved an extra serialized dispatch costs ~3 us).
// Block = 32 tokens; 256 blocks x 512 thr; ~115 KB LDS (1 block/CU).
//  P1: 24 (mat,ntile,mtile) tile-jobs, 3/wave: 6 MFMA + cos/DPP-scan epilogue.
//  P2 (waves 0-3): row-per-lane attention, 8 tok/wave (R12-verified).
//  P3: 8 (mtile,ntile) jobs, 1/wave: 6 MFMA, direct coalesced global store.

typedef float  f32x4  __attribute__((ext_vector_type(4)));
typedef short  bf16x8 __attribute__((ext_vector_type(8)));
typedef unsigned short u16;
typedef unsigned int   u32;

#define WRS 72   // shorts per row (64 data + 8 pad) = 144 B, 16B-aligned
#define SPS 68   // sP row stride (dwords), 16B-aligned

// d *= dpp_row_shr<sh>(d) gated to lanes with (lane&7) >= sh
#define DPP_SHR_STEP(d, j, sh)                                                 \
    {                                                                          \
        float _t = __int_as_float(__builtin_amdgcn_update_dpp(                 \
            0x3f800000, __float_as_int(d), 0x110 + sh, 0xf, 0xf, false));      \
        d *= ((j) >= (sh)) ? _t : 1.0f;                                        \
    }

__device__ __forceinline__ u32 bfh(float f) {          // RTNE bf16 (raw u16)
    const u32 u = __float_as_uint(f);
    return (u + 0x7FFFu + ((u >> 16) & 1u)) >> 16;
}
// trunc-hi split of a pair, packed (R13/R14-verified accuracy ~2^-17)
__device__ __forceinline__ void bfsplit2(float a, float b, u32& h, u32& l) {
    const u32 ua = __float_as_uint(a), ub = __float_as_uint(b);
    h = (ua >> 16) | (ub & 0xFFFF0000u);
    const float ra = a - __uint_as_float(ua & 0xFFFF0000u);   // exact
    const float rb = b - __uint_as_float(ub & 0xFFFF0000u);   // exact
    l = bfh(ra) | (bfh(rb) << 16);
}

#define MFMA3(acc, ah, al, bh, bl)                                             \
    acc = __builtin_amdgcn_mfma_f32_16x16x32_bf16(al, bh, acc, 0, 0, 0);       \
    acc = __builtin_amdgcn_mfma_f32_16x16x32_bf16(ah, bl, acc, 0, 0, 0);       \
    acc = __builtin_amdgcn_mfma_f32_16x16x32_bf16(ah, bh, acc, 0, 0, 0);

__global__ __launch_bounds__(512, 1)
void qattn_fused(const float* __restrict__ xg,
                 const float* __restrict__ wqg, const float* __restrict__ wkg,
                 const float* __restrict__ wvg, const float* __restrict__ wog,
                 const float* __restrict__ thg,
                 float* __restrict__ outg)
{
    __shared__ u16 sWh[4 * 64 * WRS];              // 36.9 KB  W hi (q,k,v,o)
    __shared__ u16 sWl[4 * 64 * WRS];              // 36.9 KB  W lo
    __shared__ u16 sXh[32 * WRS];                  // 4.6 KB   x hi
    __shared__ u16 sXl[32 * WRS];                  // 4.6 KB   x lo
    __shared__ __align__(16) float sP[96 * SPS];   // 26.1 KB  z values [m*32+t][e]
    __shared__ u16 sSh[32 * WRS];                  // 4.6 KB   scr hi [rho][col]
    __shared__ u16 sSl[32 * WRS];                  // 4.6 KB   scr lo

    const int tid  = threadIdx.x;
    const int lane = tid & 63;
    const int wg   = tid >> 6;         // 0..7
    const int l15  = lane & 15;
    const int quad = lane >> 4;
    const int j    = lane & 7;
    const int b    = blockIdx.x >> 4;
    const int grp  = blockIdx.x & 15;  // 32-token group in batch row

    // ---- stage W: float8 chunks -> ONE b128 write per buffer per chunk ----
    {
        const float* gm[4] = {wqg, wkg, wvg, wog};
        #pragma unroll
        for (int r = 0; r < 4; ++r) {
            const int fi = r * 512 + tid;          // float8 chunk 0..2047
            const int m  = fi >> 9;                // 512 chunks per matrix
            const int f8 = fi & 511;
            const int e  = f8 >> 3, c8 = f8 & 7;
            const float* src = gm[m] + e * 64 + c8 * 8;
            const float4 v0 = *(const float4*)src;
            const float4 v1 = *(const float4*)(src + 4);
            u32 h0, l0, h1, l1, h2, l2, h3, l3;
            bfsplit2(v0.x, v0.y, h0, l0); bfsplit2(v0.z, v0.w, h1, l1);
            bfsplit2(v1.x, v1.y, h2, l2); bfsplit2(v1.z, v1.w, h3, l3);
            const int o = (m * 64 + e) * WRS + 8 * c8;   // 16B-aligned
            *(uint4*)&sWh[o] = make_uint4(h0, h1, h2, h3);
            *(uint4*)&sWl[o] = make_uint4(l0, l1, l2, l3);
        }
    }
    // ---- stage x (32 tokens): threads 0..255, one float8 chunk each ----
    if (tid < 256) {
        const int e = tid >> 3, c8 = tid & 7;      // token e, chunk c8
        const float* src = xg + (size_t)(b * 512 + grp * 32 + e) * 64 + c8 * 8;
        const float4 v0 = *(const float4*)src;
        const float4 v1 = *(const float4*)(src + 4);
        u32 h0, l0, h1, l1, h2, l2, h3, l3;
        bfsplit2(v0.x, v0.y, h0, l0); bfsplit2(v0.z, v0.w, h1, l1);
        bfsplit2(v1.x, v1.y, h2, l2); bfsplit2(v1.z, v1.w, h3, l3);
        const int o = e * WRS + 8 * c8;
        *(uint4*)&sXh[o] = make_uint4(h0, h1, h2, h3);
        *(uint4*)&sXl[o] = make_uint4(l0, l1, l2, l3);
    }
    const float thf = thg[j];
    __syncthreads();                                 // B1: stages ready

    // ---- P1: projections via MFMA; 3 tile-jobs per wave ----
    #pragma unroll
    for (int ia = 0; ia < 3; ++ia) {
        const int aid = wg * 3 + ia;                 // 0..23
        const int mt = aid & 1, nt = (aid >> 1) & 3, m = aid >> 3;
        const int arow = (mt * 16 + l15) * WRS + quad * 8;
        const int brow = (m * 64 + nt * 16 + l15) * WRS + quad * 8;
        const bf16x8 ah0 = *(const bf16x8*)&sXh[arow];
        const bf16x8 ah1 = *(const bf16x8*)&sXh[arow + 32];
        const bf16x8 al0 = *(const bf16x8*)&sXl[arow];
        const bf16x8 al1 = *(const bf16x8*)&sXl[arow + 32];
        const bf16x8 bh0 = *(const bf16x8*)&sWh[brow];
        const bf16x8 bh1 = *(const bf16x8*)&sWh[brow + 32];
        const bf16x8 bl0 = *(const bf16x8*)&sWl[brow];
        const bf16x8 bl1 = *(const bf16x8*)&sWl[brow + 32];
        f32x4 acc = {0.f, 0.f, 0.f, 0.f};
        MFMA3(acc, ah0, al0, bh0, bl0)               // k = 0..31
        MFMA3(acc, ah1, al1, bh1, bl1)               // k = 32..63
        // epilogue: lane holds q[token][e] for 4 tokens; e = nt*16 + l15
        #pragma unroll
        for (int r = 0; r < 4; ++r) {
            const float c = __cosf(acc[r] + thf);
            float d = c;                             // inclusive scan (c0..cj)
            DPP_SHR_STEP(d, j, 1)
            DPP_SHR_STEP(d, j, 2)
            DPP_SHR_STEP(d, j, 4)
            float ex = (j == 0) ? 1.0f : c;          // scan excluding c0
            DPP_SHR_STEP(ex, j, 1)
            DPP_SHR_STEP(ex, j, 2)
            DPP_SHR_STEP(ex, j, 4)
            const int row  = m * 32 + mt * 16 + quad * 4 + r;
            const int base = row * SPS + nt * 16 + l15;
            if (j > 0)  sP[base]     = d;            // z_j = c0..cj
            if (j == 7) sP[base - 7] = ex;           // z_0 = c1..c7 -> slot 0
        }
    }
    __syncthreads();                                 // B2: z ready

    // ---- P2 (waves 0-3): row-per-lane attention, 8 tokens/wave ----
    if (wg < 4) {
        const int tg = wg * 8 + (lane >> 3);         // block-local token 0..31
        const int i  = j;                            // head (score row)
        const int qb = tg * SPS;
        const int kb = (32 + tg) * SPS;
        const int vb = (64 + tg) * SPS;
        float q[8];
        *(float4*)&q[0] = *(const float4*)&sP[qb + 8 * i];
        *(float4*)&q[4] = *(const float4*)&sP[qb + 8 * i + 4];
        float pr[8];
        float sum = 0.f;
        #pragma unroll
        for (int jj = 0; jj < 8; ++jj) {             // |s| <= 2.83 -> no max-sub
            const float4 k0 = *(const float4*)&sP[kb + 8 * jj];
            const float4 k1 = *(const float4*)&sP[kb + 8 * jj + 4];
            float s = q[0] * k0.x;
            s = fmaf(q[1], k0.y, s); s = fmaf(q[2], k0.z, s);
            s = fmaf(q[3], k0.w, s); s = fmaf(q[4], k1.x, s);
            s = fmaf(q[5], k1.y, s); s = fmaf(q[6], k1.z, s);
            s = fmaf(q[7], k1.w, s);
            pr[jj] = __expf(s * 0.35355339059327373f);
            sum += pr[jj];
        }
        const float rinv = 1.0f / sum;
        float o[8];
        #pragma unroll
        for (int w = 0; w < 8; ++w) o[w] = 0.f;
        #pragma unroll
        for (int jj = 0; jj < 8; ++jj) {
            const float4 v0 = *(const float4*)&sP[vb + 8 * jj];
            const float4 v1 = *(const float4*)&sP[vb + 8 * jj + 4];
            const float a = pr[jj] * rinv;
            o[0] = fmaf(a, v0.x, o[0]); o[1] = fmaf(a, v0.y, o[1]);
            o[2] = fmaf(a, v0.z, o[2]); o[3] = fmaf(a, v0.w, o[3]);
            o[4] = fmaf(a, v1.x, o[4]); o[5] = fmaf(a, v1.y, o[5]);
            o[6] = fmaf(a, v1.z, o[6]); o[7] = fmaf(a, v1.w, o[7]);
        }
        // scrambled row rho = i*4 + (tg>>3); col base 8*(tg&7); split-bf16
        u32 hh[4], ll[4];
        #pragma unroll
        for (int c = 0; c < 4; ++c)
            bfsplit2(o[2 * c], o[2 * c + 1], hh[c], ll[c]);
        const int so = (i * 4 + (tg >> 3)) * WRS + 8 * (tg & 7);
        *(uint4*)&sSh[so] = make_uint4(hh[0], hh[1], hh[2], hh[3]);
        *(uint4*)&sSl[so] = make_uint4(ll[0], ll[1], ll[2], ll[3]);
    }
    __syncthreads();                                 // B3: scr ready

    // ---- P3: y = scr @ Wo^T via MFMA; 1 tile-job per wave ----
    {
        const int mt2 = wg >> 2, nt2 = wg & 3;
        const int arow = (mt2 * 16 + l15) * WRS + quad * 8;
        const int brow = (3 * 64 + nt2 * 16 + l15) * WRS + quad * 8;
        const bf16x8 ah0 = *(const bf16x8*)&sSh[arow];
        const bf16x8 ah1 = *(const bf16x8*)&sSh[arow + 32];
        const bf16x8 al0 = *(const bf16x8*)&sSl[arow];
        const bf16x8 al1 = *(const bf16x8*)&sSl[arow + 32];
        const bf16x8 bh0 = *(const bf16x8*)&sWh[brow];
        const bf16x8 bh1 = *(const bf16x8*)&sWh[brow + 32];
        const bf16x8 bl0 = *(const bf16x8*)&sWl[brow];
        const bf16x8 bl1 = *(const bf16x8*)&sWl[brow + 32];
        f32x4 acc = {0.f, 0.f, 0.f, 0.f};
        MFMA3(acc, ah0, al0, bh0, bl0)
        MFMA3(acc, ah1, al1, bh1, bl1)
        // store: lane holds y[rho][e] for 4 rho; rho -> global row
        const int e = nt2 * 16 + l15;
        #pragma unroll
        for (int r = 0; r < 4; ++r) {
            const int rho = mt2 * 16 + quad * 4 + r;
            const int R   = (rho >> 2) * 64 + grp * 4 + (rho & 3);
            outg[((size_t)(b * 512 + R)) * 64 + e] = acc[r];
        }
    }
}

extern "C" void kernel_launch(void* const* d_in, const int* in_sizes, int n_in,
                              void* d_out, int out_size, void* d_ws, size_t ws_size,
                              hipStream_t stream) {
    const float* x  = (const float*)d_in[0];
    const float* wq = (const float*)d_in[1];
    const float* wk = (const float*)d_in[2];
    const float* wv = (const float*)d_in[3];
    const float* wo = (const float*)d_in[4];
    const float* th = (const float*)d_in[5];
    float* out = (float*)d_out;
    // B=16, S=512: 16 batches x 16 thirty-two-token groups = 256 blocks
    qattn_fused<<<dim3(256), dim3(512), 0, stream>>>(x, wq, wk, wv, wo, th, out);
}

// Round 17
// 68.265 us; speedup vs baseline: 1.0337x; 1.0088x over previous
//
#include <hip/hip_runtime.h>

// Analytic collapse (verified R1-R15, absmax 9.8e-4):
//   <Z_0> = c1*...*c7,  <Z_j> = c0*...*cj,  c_j = cos(t_j + theta_j)
// R16 = R12 verbatim (empirical optimum: 66.9 us bench, ~7.2 us kernel).
// R13 (no W staging), R14 (pre-split + 2nd dispatch), R15 (b128 staging +
// trunc split) all measured worse -> R12's balance of LDS-staged fragments,
// single dispatch, and double-RTNE split is the floor of this design space.
// Block = 32 tokens; 256 blocks x 512 thr; ~115 KB LDS (1 block/CU).
// All GEMMs: mfma_f32_16x16x32_bf16 with SPLIT-BF16 operands (hi+lo,
// 3 MFMAs hh+hl+lh -> ~2^-16 rel error, reproduces the fp32 path).
// Layouts (guide-verified): A[m=lane&15][k=(lane>>4)*8+j]; C col=lane&15,
// row=(lane>>4)*4+reg -> DPP scans over lane&7 survive unchanged.
// Rows padded to 72 bf16 (144 B): fragment b128s conflict-free.
//  P1: 24 (mat,ntile,mtile) tile-jobs, 3/wave: 6 MFMA + cos/DPP-scan epilogue.
//  P2 (waves 0-3): row-per-lane attention, fp32, 8 tok/wave.
//  P3: 8 (mtile,ntile) jobs, 1/wave: 6 MFMA, direct coalesced global store.

typedef float  f32x4  __attribute__((ext_vector_type(4)));
typedef short  bf16x8 __attribute__((ext_vector_type(8)));
typedef unsigned short u16;
typedef unsigned int   u32;

#define WRS 72   // shorts per row (64 data + 8 pad) = 144 B, 16B-aligned
#define SPS 68   // sP row stride (dwords), 16B-aligned

// d *= dpp_row_shr<sh>(d) gated to lanes with (lane&7) >= sh
#define DPP_SHR_STEP(d, j, sh)                                                 \
    {                                                                          \
        float _t = __int_as_float(__builtin_amdgcn_update_dpp(                 \
            0x3f800000, __float_as_int(d), 0x110 + sh, 0xf, 0xf, false));      \
        d *= ((j) >= (sh)) ? _t : 1.0f;                                        \
    }

__device__ __forceinline__ u32 bfh(float f) {          // RTNE bf16 (raw u16)
    const u32 u = __float_as_uint(f);
    return (u + 0x7FFFu + ((u >> 16) & 1u)) >> 16;
}
__device__ __forceinline__ void bfsplit(float f, u32& h, u32& l) {
    h = bfh(f);
    l = bfh(f - __uint_as_float(h << 16));
}

#define MFMA3(acc, ah, al, bh, bl)                                             \
    acc = __builtin_amdgcn_mfma_f32_16x16x32_bf16(al, bh, acc, 0, 0, 0);       \
    acc = __builtin_amdgcn_mfma_f32_16x16x32_bf16(ah, bl, acc, 0, 0, 0);       \
    acc = __builtin_amdgcn_mfma_f32_16x16x32_bf16(ah, bh, acc, 0, 0, 0);

__global__ __launch_bounds__(512, 1)
void qattn_fused(const float* __restrict__ xg,
                 const float* __restrict__ wqg, const float* __restrict__ wkg,
                 const float* __restrict__ wvg, const float* __restrict__ wog,
                 const float* __restrict__ thg,
                 float* __restrict__ outg)
{
    __shared__ u16 sWh[4 * 64 * WRS];              // 36.9 KB  W hi (q,k,v,o)
    __shared__ u16 sWl[4 * 64 * WRS];              // 36.9 KB  W lo
    __shared__ u16 sXh[32 * WRS];                  // 4.6 KB   x hi
    __shared__ u16 sXl[32 * WRS];                  // 4.6 KB   x lo
    __shared__ __align__(16) float sP[96 * SPS];   // 26.1 KB  z values [m*32+t][e]
    __shared__ u16 sSh[32 * WRS];                  // 4.6 KB   scr hi [rho][col]
    __shared__ u16 sSl[32 * WRS];                  // 4.6 KB   scr lo

    const int tid  = threadIdx.x;
    const int lane = tid & 63;
    const int wg   = tid >> 6;         // 0..7
    const int l15  = lane & 15;
    const int quad = lane >> 4;
    const int j    = lane & 7;
    const int b    = blockIdx.x >> 4;
    const int grp  = blockIdx.x & 15;  // 32-token group in batch row

    // ---- stage W (4 matrices) as split bf16, padded rows ----
    {
        const float* gm[4] = {wqg, wkg, wvg, wog};
        #pragma unroll
        for (int r = 0; r < 8; ++r) {
            const int m   = r >> 1;
            const int idx = (r & 1) * 512 + tid;         // float4 idx in matrix
            const float4 v = ((const float4*)gm[m])[idx];
            const int e = idx >> 4, c = idx & 15;
            u32 h0, l0, h1, l1, h2, l2, h3, l3;
            bfsplit(v.x, h0, l0); bfsplit(v.y, h1, l1);
            bfsplit(v.z, h2, l2); bfsplit(v.w, h3, l3);
            const int o = (m * 64 + e) * WRS + 4 * c;
            *(uint2*)&sWh[o] = make_uint2(h0 | (h1 << 16), h2 | (h3 << 16));
            *(uint2*)&sWl[o] = make_uint2(l0 | (l1 << 16), l2 | (l3 << 16));
        }
    }
    // ---- stage x (32 tokens) as split bf16 ----
    {
        const float4 v = ((const float4*)(xg + (size_t)(b * 512 + grp * 32) * 64))[tid];
        const int t = tid >> 4, c = tid & 15;
        u32 h0, l0, h1, l1, h2, l2, h3, l3;
        bfsplit(v.x, h0, l0); bfsplit(v.y, h1, l1);
        bfsplit(v.z, h2, l2); bfsplit(v.w, h3, l3);
        const int o = t * WRS + 4 * c;
        *(uint2*)&sXh[o] = make_uint2(h0 | (h1 << 16), h2 | (h3 << 16));
        *(uint2*)&sXl[o] = make_uint2(l0 | (l1 << 16), l2 | (l3 << 16));
    }
    const float thf = thg[j];
    __syncthreads();                                 // B1: stages ready

    // ---- P1: projections via MFMA; 3 tile-jobs per wave ----
    #pragma unroll
    for (int ia = 0; ia < 3; ++ia) {
        const int aid = wg * 3 + ia;                 // 0..23
        const int mt = aid & 1, nt = (aid >> 1) & 3, m = aid >> 3;
        const int arow = (mt * 16 + l15) * WRS + quad * 8;
        const int brow = (m * 64 + nt * 16 + l15) * WRS + quad * 8;
        const bf16x8 ah0 = *(const bf16x8*)&sXh[arow];
        const bf16x8 ah1 = *(const bf16x8*)&sXh[arow + 32];
        const bf16x8 al0 = *(const bf16x8*)&sXl[arow];
        const bf16x8 al1 = *(const bf16x8*)&sXl[arow + 32];
        const bf16x8 bh0 = *(const bf16x8*)&sWh[brow];
        const bf16x8 bh1 = *(const bf16x8*)&sWh[brow + 32];
        const bf16x8 bl0 = *(const bf16x8*)&sWl[brow];
        const bf16x8 bl1 = *(const bf16x8*)&sWl[brow + 32];
        f32x4 acc = {0.f, 0.f, 0.f, 0.f};
        MFMA3(acc, ah0, al0, bh0, bl0)               // k = 0..31
        MFMA3(acc, ah1, al1, bh1, bl1)               // k = 32..63
        // epilogue: lane holds q[token][e] for 4 tokens; e = nt*16 + l15
        #pragma unroll
        for (int r = 0; r < 4; ++r) {
            const float c = __cosf(acc[r] + thf);
            float d = c;                             // inclusive scan (c0..cj)
            DPP_SHR_STEP(d, j, 1)
            DPP_SHR_STEP(d, j, 2)
            DPP_SHR_STEP(d, j, 4)
            float ex = (j == 0) ? 1.0f : c;          // scan excluding c0
            DPP_SHR_STEP(ex, j, 1)
            DPP_SHR_STEP(ex, j, 2)
            DPP_SHR_STEP(ex, j, 4)
            const int row  = m * 32 + mt * 16 + quad * 4 + r;
            const int base = row * SPS + nt * 16 + l15;
            if (j > 0)  sP[base]     = d;            // z_j = c0..cj
            if (j == 7) sP[base - 7] = ex;           // z_0 = c1..c7 -> slot 0
        }
    }
    __syncthreads();                                 // B2: z ready

    // ---- P2 (waves 0-3): row-per-lane attention, 8 tokens/wave ----
    if (wg < 4) {
        const int tg = wg * 8 + (lane >> 3);         // block-local token 0..31
        const int i  = j;                            // head (score row)
        const int qb = tg * SPS;
        const int kb = (32 + tg) * SPS;
        const int vb = (64 + tg) * SPS;
        float q[8];
        *(float4*)&q[0] = *(const float4*)&sP[qb + 8 * i];
        *(float4*)&q[4] = *(const float4*)&sP[qb + 8 * i + 4];
        float pr[8];
        float sum = 0.f;
        #pragma unroll
        for (int jj = 0; jj < 8; ++jj) {             // |s| <= 2.83 -> no max-sub
            const float4 k0 = *(const float4*)&sP[kb + 8 * jj];
            const float4 k1 = *(const float4*)&sP[kb + 8 * jj + 4];
            float s = q[0] * k0.x;
            s = fmaf(q[1], k0.y, s); s = fmaf(q[2], k0.z, s);
            s = fmaf(q[3], k0.w, s); s = fmaf(q[4], k1.x, s);
            s = fmaf(q[5], k1.y, s); s = fmaf(q[6], k1.z, s);
            s = fmaf(q[7], k1.w, s);
            pr[jj] = __expf(s * 0.35355339059327373f);
            sum += pr[jj];
        }
        const float rinv = 1.0f / sum;
        float o[8];
        #pragma unroll
        for (int w = 0; w < 8; ++w) o[w] = 0.f;
        #pragma unroll
        for (int jj = 0; jj < 8; ++jj) {
            const float4 v0 = *(const float4*)&sP[vb + 8 * jj];
            const float4 v1 = *(const float4*)&sP[vb + 8 * jj + 4];
            const float a = pr[jj] * rinv;
            o[0] = fmaf(a, v0.x, o[0]); o[1] = fmaf(a, v0.y, o[1]);
            o[2] = fmaf(a, v0.z, o[2]); o[3] = fmaf(a, v0.w, o[3]);
            o[4] = fmaf(a, v1.x, o[4]); o[5] = fmaf(a, v1.y, o[5]);
            o[6] = fmaf(a, v1.z, o[6]); o[7] = fmaf(a, v1.w, o[7]);
        }
        // scrambled row rho = i*4 + (tg>>3); col base 8*(tg&7); split-bf16
        u32 hh[4], ll[4];
        #pragma unroll
        for (int c = 0; c < 4; ++c) {
            u32 ha, la, hb, lb;
            bfsplit(o[2 * c], ha, la);
            bfsplit(o[2 * c + 1], hb, lb);
            hh[c] = ha | (hb << 16);
            ll[c] = la | (lb << 16);
        }
        const int so = (i * 4 + (tg >> 3)) * WRS + 8 * (tg & 7);
        *(uint4*)&sSh[so] = make_uint4(hh[0], hh[1], hh[2], hh[3]);
        *(uint4*)&sSl[so] = make_uint4(ll[0], ll[1], ll[2], ll[3]);
    }
    __syncthreads();                                 // B3: scr ready

    // ---- P3: y = scr @ Wo^T via MFMA; 1 tile-job per wave ----
    {
        const int mt2 = wg >> 2, nt2 = wg & 3;
        const int arow = (mt2 * 16 + l15) * WRS + quad * 8;
        const int brow = (3 * 64 + nt2 * 16 + l15) * WRS + quad * 8;
        const bf16x8 ah0 = *(const bf16x8*)&sSh[arow];
        const bf16x8 ah1 = *(const bf16x8*)&sSh[arow + 32];
        const bf16x8 al0 = *(const bf16x8*)&sSl[arow];
        const bf16x8 al1 = *(const bf16x8*)&sSl[arow + 32];
        const bf16x8 bh0 = *(const bf16x8*)&sWh[brow];
        const bf16x8 bh1 = *(const bf16x8*)&sWh[brow + 32];
        const bf16x8 bl0 = *(const bf16x8*)&sWl[brow];
        const bf16x8 bl1 = *(const bf16x8*)&sWl[brow + 32];
        f32x4 acc = {0.f, 0.f, 0.f, 0.f};
        MFMA3(acc, ah0, al0, bh0, bl0)
        MFMA3(acc, ah1, al1, bh1, bl1)
        // store: lane holds y[rho][e] for 4 rho; rho -> global row
        const int e = nt2 * 16 + l15;
        #pragma unroll
        for (int r = 0; r < 4; ++r) {
            const int rho = mt2 * 16 + quad * 4 + r;
            const int R   = (rho >> 2) * 64 + grp * 4 + (rho & 3);
            outg[((size_t)(b * 512 + R)) * 64 + e] = acc[r];
        }
    }
}

extern "C" void kernel_launch(void* const* d_in, const int* in_sizes, int n_in,
                              void* d_out, int out_size, void* d_ws, size_t ws_size,
                              hipStream_t stream) {
    const float* x  = (const float*)d_in[0];
    const float* wq = (const float*)d_in[1];
    const float* wk = (const float*)d_in[2];
    const float* wv = (const float*)d_in[3];
    const float* wo = (const float*)d_in[4];
    const float* th = (const float*)d_in[5];
    float* out = (float*)d_out;
    // B=16, S=512: 16 batches x 16 thirty-two-token groups = 256 blocks
    qattn_fused<<<dim3(256), dim3(512), 0, stream>>>(x, wq, wk, wv, wo, th, out);
}